// Round 11
// baseline (1151.680 us; speedup 1.0000x reference)
//
#include <hip/hip_runtime.h>
#include <hip/hip_bf16.h>

// TreeHopNode: h = q - rep + (per-head MLP(sigmoid(Qh*Kh/16)*Vh)) @ Ws
// N=65536, E=1024, H=4, G=256, MLP=256. bf16 MFMA 16x16x32, f32 accum.
//
// R11 = R10 with ONE change: LDS 128KB -> 64KB per block (4 slots -> 2)
// => 2 blocks/CU. R6-R10 all ran 1 block/CU where the 2-barrier phase makes
// LDS-read and MFMA windows strictly disjoint block-wide (serial model:
// ~190cy LDS + ~155cy MFMA + barriers => 35% MfmaUtil ceiling; measured 31%).
// A second resident block overlaps its MFMA with this block's LDS/barrier
// window (m114 co-scheduling). Cost: depth-1 prefetch => vmcnt(0) gate once
// per slice; the co-resident block covers the drain.
// Ledger: WAR - slot (s+1)&1 last read in (s-1,MH1), proven serviced by that
// phase's post-barrier lgkmcnt(0), which precedes the stage issue in (s,MH0).
// RAW - vmcnt(0)+barrier at end of (s,MH1) proves slot landed block-wide
// before (s+1,MH0) reads. Tail clamps SOURCE only.

typedef __attribute__((ext_vector_type(8))) short bf16x8;
typedef __attribute__((ext_vector_type(4))) float f32x4;
typedef __attribute__((ext_vector_type(4))) short short4v;

#define AS1 __attribute__((address_space(1)))
#define AS3 __attribute__((address_space(3)))

static __device__ __forceinline__ short f2b(float x) {
  __hip_bfloat16 h = __float2bfloat16(x);
  return __builtin_bit_cast(short, h);
}
static __device__ __forceinline__ float b2f(short s) {
  unsigned u = ((unsigned)(unsigned short)s) << 16;
  return __builtin_bit_cast(float, u);
}

// ---------------- convert f32 -> bf16, vectorized ----------------
__global__ void cvt_bf16(const float* __restrict__ in, short* __restrict__ out, long n) {
  long i = ((long)blockIdx.x * blockDim.x + threadIdx.x) * 4;
  const long stride = (long)gridDim.x * blockDim.x * 4;
  for (; i < n; i += stride) {
    float4 v = *(const float4*)(in + i);
    short4v o = { f2b(v.x), f2b(v.y), f2b(v.z), f2b(v.w) };
    *(short4v*)(out + i) = o;
  }
}

// ---------------- transpose + convert weights ----------------
__global__ void prep_weights(
    const float* __restrict__ Wq, const float* __restrict__ Wk, const float* __restrict__ Wv,
    const float* __restrict__ W1, const float* __restrict__ W2, const float* __restrict__ Ws,
    short* __restrict__ wqt, short* __restrict__ wkt, short* __restrict__ wvt,
    short* __restrict__ w1t, short* __restrict__ w2t, short* __restrict__ wst)
{
  const int job = blockIdx.z;
  const float* src; short* dst; int R, C;
  if (job < 3)       { src = (job==0)?Wq:((job==1)?Wk:Wv); dst = (job==0)?wqt:((job==1)?wkt:wvt); R = 1024; C = 1024; }
  else if (job == 3) { src = Ws; dst = wst; R = 1024; C = 1024; }
  else if (job < 8)  { int h = job-4; src = W1 + h*65536; dst = w1t + h*65536; R = 256; C = 256; }
  else               { int h = job-8; src = W2 + h*65536; dst = w2t + h*65536; R = 256; C = 256; }
  const int c0 = blockIdx.x * 32, r0 = blockIdx.y * 32;
  if (c0 >= C || r0 >= R) return;
  __shared__ float t[32][33];
  for (int i = threadIdx.y; i < 32; i += 8)
    t[i][threadIdx.x] = src[(long)(r0 + i) * C + c0 + threadIdx.x];
  __syncthreads();
  for (int i = threadIdx.y; i < 32; i += 8)
    dst[(long)(c0 + i) * R + r0 + threadIdx.x] = f2b(t[threadIdx.x][i]);
}

// ---------------- 256x256-tile bf16 GEMM, 2-slot / 2 blocks/CU ----------
// C = ep(A @ Bt^T); Bt stored [col][k]. blockIdx.z batches heads (strides).
// RESID: f32 out = b2f(qres[gi]) - b2f(rres[gi]) + acc
template <int KDIM, int LDA, int LDB, bool RELU, bool BIAS, bool RESID, bool SWZ>
__global__ __launch_bounds__(512, 2) void gemm_bf16(
    const short* __restrict__ A, long zsa,
    const short* __restrict__ Bt, long zsb,
    void* __restrict__ outv, long ldc, long zsc,
    const float* __restrict__ bias, long zsbias,
    const short* __restrict__ qres, const short* __restrict__ rres)
{
  __shared__ __align__(16) short lA[2 * 8192];     // 2 slots of [256][32]
  __shared__ __align__(16) short lB[2 * 8192];
  const int lane = threadIdx.x & 63, wave = threadIdx.x >> 6;
  const int wm = wave >> 2, wn = wave & 3;         // 2M x 4N wave grid
  int bx = blockIdx.x, by = blockIdx.y;
  if (SWZ) {
    const int nbx = gridDim.x;
    const int flat = by * nbx + bx;
    const int chunk = (int)(gridDim.x * gridDim.y) >> 3;
    const int fid = (flat & 7) * chunk + (flat >> 3);
    bx = fid % nbx; by = fid / nbx;
  }
  const long bm = (long)by * 256;
  const int  bn = bx * 256;
  const int  zi = blockIdx.z;

  const short* Ab = A + (long)zi * zsa + bm * LDA;
  const short* Bb = Bt + (long)zi * zsb + (long)bn * LDB;
  constexpr int NS = KDIM / 32;                    // k-slices (32 wide)
  const int g0 = lane >> 4;
  const int arow = wm * 128 + (lane & 15);
  const int bcol = wn * 64 + (lane & 15);

  // precomputed swizzled LDS read bases (slot-invariant XOR)
  const char* aP = (const char*)lA + arow * 64 + (((g0 ^ (arow >> 1)) & 3) << 4);
  const char* bP = (const char*)lB + bcol * 64 + (((g0 ^ (bcol >> 1)) & 3) << 4);

  // precomputed stage pointers
  const int rw = lane >> 2;                        // row within 16-row slab
  const int gg = (lane & 3) ^ ((rw >> 1) & 3);     // swizzled source granule
  const short* Asrc = Ab + (wave * 16 + rw) * LDA + (gg << 3);
  const short* Bsrc = Bb + (wave * 16 + rw) * LDB + (gg << 3);
  short* lAd = lA + wave * 16 * 32;                // + slot*8192 + j*4096
  short* lBd = lB + wave * 16 * 32;

  auto stA = [&](int slot, int s) {
    const int sc = s < NS ? s : NS - 1;            // tail: clamp SOURCE only
    const short* src = Asrc + sc * 32;
    short* d = lAd + slot * 8192;
    __builtin_amdgcn_global_load_lds((const AS1 void*)src,              (AS3 void*)d,        16, 0, 0);
    __builtin_amdgcn_global_load_lds((const AS1 void*)(src + 128*LDA),  (AS3 void*)(d+4096), 16, 0, 0);
  };
  auto stB = [&](int slot, int s) {
    const int sc = s < NS ? s : NS - 1;
    const short* src = Bsrc + sc * 32;
    short* d = lBd + slot * 8192;
    __builtin_amdgcn_global_load_lds((const AS1 void*)src,              (AS3 void*)d,        16, 0, 0);
    __builtin_amdgcn_global_load_lds((const AS1 void*)(src + 128*LDB),  (AS3 void*)(d+4096), 16, 0, 0);
  };

  // prologue: slice 0 only (depth-1); vmcnt(0) proves it
  stA(0, 0); stB(0, 0);
  asm volatile("s_waitcnt vmcnt(0)" ::: "memory");
  __builtin_amdgcn_s_barrier();

  f32x4 acc[8][4] = {};
  bf16x8 b[4];

#define PHASE(SLOT, MH, LOADB, STAGE_STMT, DOVM)                            \
  {                                                                         \
    if (LOADB) {                                                            \
      _Pragma("unroll")                                                     \
      for (int j = 0; j < 4; ++j)                                           \
        b[j] = *(const bf16x8*)(bP + (SLOT) * 16384 + j * 1024);            \
    }                                                                       \
    bf16x8 a[4];                                                            \
    _Pragma("unroll")                                                       \
    for (int i2 = 0; i2 < 4; ++i2)                                          \
      a[i2] = *(const bf16x8*)(aP + (SLOT) * 16384 + (MH) * 4096 + i2 * 1024); \
    STAGE_STMT;                                                             \
    if (DOVM) asm volatile("s_waitcnt vmcnt(0)" ::: "memory");              \
    asm volatile("" ::: "memory");                                          \
    __builtin_amdgcn_s_barrier();                                           \
    asm volatile("s_waitcnt lgkmcnt(0)" ::: "memory");                      \
    __builtin_amdgcn_sched_barrier(0);                                      \
    __builtin_amdgcn_s_setprio(1);                                          \
    _Pragma("unroll")                                                       \
    for (int i2 = 0; i2 < 4; ++i2)                                          \
      _Pragma("unroll")                                                     \
      for (int j = 0; j < 4; ++j)                                           \
        acc[(MH) * 4 + i2][j] = __builtin_amdgcn_mfma_f32_16x16x32_bf16(    \
            a[i2], b[j], acc[(MH) * 4 + i2][j], 0, 0, 0);                   \
    __builtin_amdgcn_s_setprio(0);                                          \
    asm volatile("" ::: "memory");                                          \
    __builtin_amdgcn_s_barrier();                                           \
  }

  for (int s = 0; s < NS; s += 2) {
    PHASE(0, 0, true,  stA(1, s + 1), false) PHASE(0, 1, false, stB(1, s + 1), true)
    PHASE(1, 0, true,  stA(0, s + 2), false) PHASE(1, 1, false, stB(0, s + 2), true)
  }
#undef PHASE

  // epilogue; C/D layout: col=lane&15, row=(lane>>4)*4+reg (m89)
  #pragma unroll
  for (int i = 0; i < 8; ++i)
    #pragma unroll
    for (int j = 0; j < 4; ++j)
      #pragma unroll
      for (int r = 0; r < 4; ++r) {
        const int rl = wm * 128 + i * 16 + ((lane >> 4) << 2) + r;
        const int cl = wn * 64 + j * 16 + (lane & 15);
        float v = acc[i][j][r];
        if (BIAS) v += bias[(long)zi * zsbias + bn + cl];
        if (RELU) v = v > 0.0f ? v : 0.0f;
        const long row = bm + rl;
        const long gi = (long)zi * zsc + row * ldc + bn + cl;
        if (RESID) {
          ((float*)outv)[gi] = b2f(qres[gi]) - b2f(rres[gi]) + v;
        } else {
          ((short*)outv)[gi] = f2b(v);
        }
      }
}

// ------------- merged G2+G3: z = sigmoid(Qh*Kh/16) * Vh -------------
// 256x128 tile, dual accumulators (Kh, Vh) sharing the staged A (rep) tile.
// Same 2-slot / 2 blocks/CU pipeline.
__global__ __launch_bounds__(512, 2) void gemm_g23(
    const short* __restrict__ rb,    // A: rep bf16 [65536][1024]
    const short* __restrict__ wkt,   // Bk [col][k]
    const short* __restrict__ wvt,   // Bv [col][k]
    const short* __restrict__ gh,    // Qh bf16 [65536][1024]
    short* __restrict__ zb)          // z bf16 out
{
  __shared__ __align__(16) short lA[2 * 8192];     // 32KB: 256 rows x 32k
  __shared__ __align__(16) short lK[2 * 4096];     // 16KB: 128 cols x 32k
  __shared__ __align__(16) short lV[2 * 4096];     // 16KB
  const int lane = threadIdx.x & 63, wave = threadIdx.x >> 6;
  const int wm = wave >> 2, wn = wave & 3;         // per-wave out: 128 x 32
  int bx = blockIdx.x, by = blockIdx.y;
  {
    const int flat = by * 8 + bx;                  // gridDim.x == 8
    const int chunk = (int)(gridDim.x * gridDim.y) >> 3;
    const int fid = (flat & 7) * chunk + (flat >> 3);
    bx = fid & 7; by = fid >> 3;
  }
  const long bm = (long)by * 256;
  const int  bn = bx * 128;

  const short* Ab = rb + bm * 1024;
  const short* Kb = wkt + (long)bn * 1024;
  const short* Vb = wvt + (long)bn * 1024;
  constexpr int NS = 32;                           // K = 1024
  const int g0 = lane >> 4;
  const int arow = wm * 128 + (lane & 15);
  const int bcol = wn * 32 + (lane & 15);

  const char* aP = (const char*)lA + arow * 64 + (((g0 ^ (arow >> 1)) & 3) << 4);
  const char* kP = (const char*)lK + bcol * 64 + (((g0 ^ (bcol >> 1)) & 3) << 4);
  const char* vP = (const char*)lV + bcol * 64 + (((g0 ^ (bcol >> 1)) & 3) << 4);

  const int rw = lane >> 2;
  const int gg = (lane & 3) ^ ((rw >> 1) & 3);
  const short* Asrc = Ab + (wave * 16 + rw) * 1024 + (gg << 3);
  const short* Ksrc = Kb + (wave * 16 + rw) * 1024 + (gg << 3);
  const short* Vsrc = Vb + (wave * 16 + rw) * 1024 + (gg << 3);
  short* lAd = lA + wave * 16 * 32;
  short* lKd = lK + wave * 16 * 32;
  short* lVd = lV + wave * 16 * 32;

  auto stA = [&](int slot, int s) {
    const int sc = s < NS ? s : NS - 1;
    const short* src = Asrc + sc * 32;
    short* d = lAd + slot * 8192;
    __builtin_amdgcn_global_load_lds((const AS1 void*)src,               (AS3 void*)d,        16, 0, 0);
    __builtin_amdgcn_global_load_lds((const AS1 void*)(src + 128*1024),  (AS3 void*)(d+4096), 16, 0, 0);
  };
  auto stKV = [&](int slot, int s) {
    const int sc = s < NS ? s : NS - 1;
    __builtin_amdgcn_global_load_lds((const AS1 void*)(Ksrc + sc * 32), (AS3 void*)(lKd + slot * 4096), 16, 0, 0);
    __builtin_amdgcn_global_load_lds((const AS1 void*)(Vsrc + sc * 32), (AS3 void*)(lVd + slot * 4096), 16, 0, 0);
  };

  // prologue: slice 0 only (depth-1); vmcnt(0) proves it
  stA(0, 0); stKV(0, 0);
  asm volatile("s_waitcnt vmcnt(0)" ::: "memory");
  __builtin_amdgcn_s_barrier();

  f32x4 ack[8][2] = {};
  f32x4 acv[8][2] = {};
  bf16x8 bk[2], bv[2];

#define PHASEG(SLOT, MH, LOADB, STAGE_STMT, DOVM)                           \
  {                                                                         \
    if (LOADB) {                                                            \
      _Pragma("unroll")                                                     \
      for (int j = 0; j < 2; ++j) {                                         \
        bk[j] = *(const bf16x8*)(kP + (SLOT) * 8192 + j * 1024);            \
        bv[j] = *(const bf16x8*)(vP + (SLOT) * 8192 + j * 1024);            \
      }                                                                     \
    }                                                                       \
    bf16x8 a[4];                                                            \
    _Pragma("unroll")                                                       \
    for (int i2 = 0; i2 < 4; ++i2)                                          \
      a[i2] = *(const bf16x8*)(aP + (SLOT) * 16384 + (MH) * 4096 + i2 * 1024); \
    STAGE_STMT;                                                             \
    if (DOVM) asm volatile("s_waitcnt vmcnt(0)" ::: "memory");              \
    asm volatile("" ::: "memory");                                          \
    __builtin_amdgcn_s_barrier();                                           \
    asm volatile("s_waitcnt lgkmcnt(0)" ::: "memory");                      \
    __builtin_amdgcn_sched_barrier(0);                                      \
    __builtin_amdgcn_s_setprio(1);                                          \
    _Pragma("unroll")                                                       \
    for (int i2 = 0; i2 < 4; ++i2)                                          \
      _Pragma("unroll")                                                     \
      for (int j = 0; j < 2; ++j) {                                         \
        ack[(MH) * 4 + i2][j] = __builtin_amdgcn_mfma_f32_16x16x32_bf16(    \
            a[i2], bk[j], ack[(MH) * 4 + i2][j], 0, 0, 0);                  \
        acv[(MH) * 4 + i2][j] = __builtin_amdgcn_mfma_f32_16x16x32_bf16(    \
            a[i2], bv[j], acv[(MH) * 4 + i2][j], 0, 0, 0);                  \
      }                                                                     \
    __builtin_amdgcn_s_setprio(0);                                          \
    asm volatile("" ::: "memory");                                          \
    __builtin_amdgcn_s_barrier();                                           \
  }

  for (int s = 0; s < NS; s += 2) {
    PHASEG(0, 0, true,  stA(1, s + 1), false) PHASEG(0, 1, false, stKV(1, s + 1), true)
    PHASEG(1, 0, true,  stA(0, s + 2), false) PHASEG(1, 1, false, stKV(0, s + 2), true)
  }
#undef PHASEG

  // epilogue: z = sigmoid(Qh * Kh / 16) * Vh
  #pragma unroll
  for (int i = 0; i < 8; ++i)
    #pragma unroll
    for (int j = 0; j < 2; ++j)
      #pragma unroll
      for (int r = 0; r < 4; ++r) {
        const int rl = wm * 128 + i * 16 + ((lane >> 4) << 2) + r;
        const int cl = wn * 32 + j * 16 + (lane & 15);
        const long gi = (bm + rl) * 1024 + bn + cl;
        const float x = b2f(gh[gi]) * ack[i][j][r] * 0.0625f;
        const float gate = 1.0f / (1.0f + __expf(-x));
        zb[gi] = f2b(gate * acv[i][j][r]);
      }
}

extern "C" void kernel_launch(void* const* d_in, const int* in_sizes, int n_in,
                              void* d_out, int out_size, void* d_ws, size_t ws_size,
                              hipStream_t stream) {
  const float* q   = (const float*)d_in[0];
  const float* rep = (const float*)d_in[1];
  const float* Wq  = (const float*)d_in[2];
  const float* Wk  = (const float*)d_in[3];
  const float* Wv  = (const float*)d_in[4];
  const float* W1  = (const float*)d_in[5];
  const float* b1  = (const float*)d_in[6];
  const float* W2  = (const float*)d_in[7];
  const float* b2  = (const float*)d_in[8];
  const float* Ws  = (const float*)d_in[9];
  float* out = (float*)d_out;

  const long NE = 67108864L;   // 65536 * 1024
  char* ws = (char*)d_ws;
  // 4 x 128 MiB slots:
  //   s0: qb (cvt..F)   s1: rb (cvt..F)
  //   s2: gh (G1..G23) -> h1 (M1..M2)
  //   s3: zb (G23..M1) -> ug (M2..F)
  short* qb  = (short*)(ws);
  short* rb  = (short*)(ws + NE * 2);
  short* gh  = (short*)(ws + NE * 4);
  short* zb  = (short*)(ws + NE * 6);
  short* h1b = gh;
  short* ugb = zb;
  char*  wp  = ws + NE * 8;
  short* wqt = (short*)(wp);                 // 2 MiB each
  short* wkt = (short*)(wp + 2097152);
  short* wvt = (short*)(wp + 4194304);
  short* wst = (short*)(wp + 6291456);
  short* w1t = (short*)(wp + 8388608);       // 512 KiB
  short* w2t = (short*)(wp + 8912896);       // 512 KiB

  cvt_bf16<<<4096, 256, 0, stream>>>(q,   qb, NE);
  cvt_bf16<<<4096, 256, 0, stream>>>(rep, rb, NE);
  prep_weights<<<dim3(32, 32, 12), dim3(32, 8), 0, stream>>>(
      Wq, Wk, Wv, W1, W2, Ws, wqt, wkt, wvt, w1t, w2t, wst);

  // G1: Qh = q @ Wq  (bf16 -> gh)
  gemm_bf16<1024, 1024, 1024, false, false, false, true><<<dim3(4, 256), 512, 0, stream>>>(
      qb, 0, wqt, 0, gh, 1024, 0, nullptr, 0, nullptr, nullptr);
  // G23: z = sigmoid(Qh * (rep@Wk) / 16) * (rep@Wv)  -> zb
  gemm_g23<<<dim3(8, 256), 512, 0, stream>>>(rb, wkt, wvt, gh, zb);

  // M1: h1 = relu(z @ W1 + b1), per head (head = blockIdx.z)
  gemm_bf16<256, 1024, 256, true, true, false, false><<<dim3(1, 256, 4), 512, 0, stream>>>(
      zb, 256, w1t, 65536, h1b, 1024, 256, b1, 256, nullptr, nullptr);
  // M2: ug = h1 @ W2 + b2, per head
  gemm_bf16<256, 1024, 256, false, true, false, false><<<dim3(1, 256, 4), 512, 0, stream>>>(
      h1b, 256, w2t, 65536, ugb, 1024, 256, b2, 256, nullptr, nullptr);
  // F: out = (q - rep) + ug @ Ws   (residual from bf16 qb/rb)
  gemm_bf16<1024, 1024, 1024, false, false, true, true><<<dim3(4, 256), 512, 0, stream>>>(
      ugb, 0, wst, 0, out, 1024, 0, nullptr, 0, qb, rb);
}

// Round 12
// 1046.082 us; speedup vs baseline: 1.1009x; 1.1009x over previous
//
#include <hip/hip_runtime.h>
#include <hip/hip_bf16.h>

// TreeHopNode: h = q - rep + (per-head MLP(sigmoid(Qh*Kh/16)*Vh)) @ Ws
// N=65536, E=1024, H=4, G=256, MLP=256. bf16 MFMA 16x16x32, f32 accum.
//
// R12 = R10 (passed, 1044us) with ONE change: remove the per-phase explicit
// "s_waitcnt lgkmcnt(0)" + sched_barrier(0) before the MFMA cluster.
// That drain forced ALL 12 ds_reads (96KB/slice block-wide, ~375cy at
// 256B/cy) to complete serially before any MFMA (155cy/SIMD) -> 31% ceiling
// (matches R6/R9/R10 exactly). Plain-C++ ds_reads are compiler-tracked:
// hipcc emits fine-grained lgkmcnt(4/3/1/0) interleaving MFMA with LDS
// service (m97 asm). Rule #18 (explicit drain) applies only to inline-asm
// reads. WAR ledger intact: a wave passing the closing barrier has issued
// all MFMAs => all its ds_reads completed.

typedef __attribute__((ext_vector_type(8))) short bf16x8;
typedef __attribute__((ext_vector_type(4))) float f32x4;
typedef __attribute__((ext_vector_type(4))) short short4v;

#define AS1 __attribute__((address_space(1)))
#define AS3 __attribute__((address_space(3)))

static __device__ __forceinline__ short f2b(float x) {
  __hip_bfloat16 h = __float2bfloat16(x);
  return __builtin_bit_cast(short, h);
}
static __device__ __forceinline__ float b2f(short s) {
  unsigned u = ((unsigned)(unsigned short)s) << 16;
  return __builtin_bit_cast(float, u);
}

// ---------------- convert f32 -> bf16, vectorized ----------------
__global__ void cvt_bf16(const float* __restrict__ in, short* __restrict__ out, long n) {
  long i = ((long)blockIdx.x * blockDim.x + threadIdx.x) * 4;
  const long stride = (long)gridDim.x * blockDim.x * 4;
  for (; i < n; i += stride) {
    float4 v = *(const float4*)(in + i);
    short4v o = { f2b(v.x), f2b(v.y), f2b(v.z), f2b(v.w) };
    *(short4v*)(out + i) = o;
  }
}

// ---------------- transpose + convert weights ----------------
__global__ void prep_weights(
    const float* __restrict__ Wq, const float* __restrict__ Wk, const float* __restrict__ Wv,
    const float* __restrict__ W1, const float* __restrict__ W2, const float* __restrict__ Ws,
    short* __restrict__ wqt, short* __restrict__ wkt, short* __restrict__ wvt,
    short* __restrict__ w1t, short* __restrict__ w2t, short* __restrict__ wst)
{
  const int job = blockIdx.z;
  const float* src; short* dst; int R, C;
  if (job < 3)       { src = (job==0)?Wq:((job==1)?Wk:Wv); dst = (job==0)?wqt:((job==1)?wkt:wvt); R = 1024; C = 1024; }
  else if (job == 3) { src = Ws; dst = wst; R = 1024; C = 1024; }
  else if (job < 8)  { int h = job-4; src = W1 + h*65536; dst = w1t + h*65536; R = 256; C = 256; }
  else               { int h = job-8; src = W2 + h*65536; dst = w2t + h*65536; R = 256; C = 256; }
  const int c0 = blockIdx.x * 32, r0 = blockIdx.y * 32;
  if (c0 >= C || r0 >= R) return;
  __shared__ float t[32][33];
  for (int i = threadIdx.y; i < 32; i += 8)
    t[i][threadIdx.x] = src[(long)(r0 + i) * C + c0 + threadIdx.x];
  __syncthreads();
  for (int i = threadIdx.y; i < 32; i += 8)
    dst[(long)(c0 + i) * R + r0 + threadIdx.x] = f2b(t[threadIdx.x][i]);
}

// ---------------- 256x256-tile bf16 GEMM, 4-slot pipeline -------------
// C = ep(A @ Bt^T); Bt stored [col][k]. blockIdx.z batches heads (strides).
// RESID: f32 out = b2f(qres[gi]) - b2f(rres[gi]) + acc
template <int KDIM, int LDA, int LDB, bool RELU, bool BIAS, bool RESID, bool SWZ>
__global__ __launch_bounds__(512, 2) void gemm_bf16(
    const short* __restrict__ A, long zsa,
    const short* __restrict__ Bt, long zsb,
    void* __restrict__ outv, long ldc, long zsc,
    const float* __restrict__ bias, long zsbias,
    const short* __restrict__ qres, const short* __restrict__ rres)
{
  __shared__ __align__(16) short lA[4 * 8192];     // 4 slots of [256][32]
  __shared__ __align__(16) short lB[4 * 8192];
  const int lane = threadIdx.x & 63, wave = threadIdx.x >> 6;
  const int wm = wave >> 2, wn = wave & 3;         // 2M x 4N wave grid
  int bx = blockIdx.x, by = blockIdx.y;
  if (SWZ) {
    const int nbx = gridDim.x;
    const int flat = by * nbx + bx;
    const int chunk = (int)(gridDim.x * gridDim.y) >> 3;
    const int fid = (flat & 7) * chunk + (flat >> 3);
    bx = fid % nbx; by = fid / nbx;
  }
  const long bm = (long)by * 256;
  const int  bn = bx * 256;
  const int  zi = blockIdx.z;

  const short* Ab = A + (long)zi * zsa + bm * LDA;
  const short* Bb = Bt + (long)zi * zsb + (long)bn * LDB;
  constexpr int NS = KDIM / 32;                    // k-slices (32 wide)
  const int g0 = lane >> 4;
  const int arow = wm * 128 + (lane & 15);
  const int bcol = wn * 64 + (lane & 15);

  // precomputed swizzled LDS read bases (slot-invariant XOR)
  const char* aP = (const char*)lA + arow * 64 + (((g0 ^ (arow >> 1)) & 3) << 4);
  const char* bP = (const char*)lB + bcol * 64 + (((g0 ^ (bcol >> 1)) & 3) << 4);

  // precomputed stage pointers
  const int rw = lane >> 2;                        // row within 16-row slab
  const int gg = (lane & 3) ^ ((rw >> 1) & 3);     // swizzled source granule
  const short* Asrc = Ab + (wave * 16 + rw) * LDA + (gg << 3);
  const short* Bsrc = Bb + (wave * 16 + rw) * LDB + (gg << 3);
  short* lAd = lA + wave * 16 * 32;                // + slot*8192 + j*4096
  short* lBd = lB + wave * 16 * 32;

  auto stA = [&](int slot, int s) {
    const int sc = s < NS ? s : NS - 1;            // tail: clamp SOURCE only
    const short* src = Asrc + sc * 32;
    short* d = lAd + slot * 8192;
    __builtin_amdgcn_global_load_lds((const AS1 void*)src,              (AS3 void*)d,        16, 0, 0);
    __builtin_amdgcn_global_load_lds((const AS1 void*)(src + 128*LDA),  (AS3 void*)(d+4096), 16, 0, 0);
  };
  auto stB = [&](int slot, int s) {
    const int sc = s < NS ? s : NS - 1;
    const short* src = Bsrc + sc * 32;
    short* d = lBd + slot * 8192;
    __builtin_amdgcn_global_load_lds((const AS1 void*)src,              (AS3 void*)d,        16, 0, 0);
    __builtin_amdgcn_global_load_lds((const AS1 void*)(src + 128*LDB),  (AS3 void*)(d+4096), 16, 0, 0);
  };

  // prologue: slices 0,1,2 (12 loads/wave); vmcnt(8) proves slice 0
  stA(0, 0); stB(0, 0);
  stA(1, 1); stB(1, 1);
  stA(2, 2); stB(2, 2);
  asm volatile("s_waitcnt vmcnt(8)" ::: "memory");
  __builtin_amdgcn_s_barrier();

  f32x4 acc[8][4] = {};
  bf16x8 b[4];

#define PHASE(SLOT, MH, LOADB, STAGE_STMT, DOVM)                            \
  {                                                                         \
    if (LOADB) {                                                            \
      _Pragma("unroll")                                                     \
      for (int j = 0; j < 4; ++j)                                           \
        b[j] = *(const bf16x8*)(bP + (SLOT) * 16384 + j * 1024);            \
    }                                                                       \
    bf16x8 a[4];                                                            \
    _Pragma("unroll")                                                       \
    for (int i2 = 0; i2 < 4; ++i2)                                          \
      a[i2] = *(const bf16x8*)(aP + (SLOT) * 16384 + (MH) * 4096 + i2 * 1024); \
    STAGE_STMT;                                                             \
    if (DOVM) asm volatile("s_waitcnt vmcnt(8)" ::: "memory");              \
    asm volatile("" ::: "memory");                                          \
    __builtin_amdgcn_s_barrier();                                           \
    __builtin_amdgcn_s_setprio(1);                                          \
    _Pragma("unroll")                                                       \
    for (int i2 = 0; i2 < 4; ++i2)                                          \
      _Pragma("unroll")                                                     \
      for (int j = 0; j < 4; ++j)                                           \
        acc[(MH) * 4 + i2][j] = __builtin_amdgcn_mfma_f32_16x16x32_bf16(    \
            a[i2], b[j], acc[(MH) * 4 + i2][j], 0, 0, 0);                   \
    __builtin_amdgcn_s_setprio(0);                                          \
    asm volatile("" ::: "memory");                                          \
    __builtin_amdgcn_s_barrier();                                           \
  }

  for (int s = 0; s < NS; s += 4) {
    PHASE(0, 0, true,  stA(3, s + 3), false) PHASE(0, 1, false, stB(3, s + 3), true)
    PHASE(1, 0, true,  stA(0, s + 4), false) PHASE(1, 1, false, stB(0, s + 4), true)
    PHASE(2, 0, true,  stA(1, s + 5), false) PHASE(2, 1, false, stB(1, s + 5), true)
    PHASE(3, 0, true,  stA(2, s + 6), false) PHASE(3, 1, false, stB(2, s + 6), true)
  }
#undef PHASE

  // epilogue; C/D layout: col=lane&15, row=(lane>>4)*4+reg (m89)
  #pragma unroll
  for (int i = 0; i < 8; ++i)
    #pragma unroll
    for (int j = 0; j < 4; ++j)
      #pragma unroll
      for (int r = 0; r < 4; ++r) {
        const int rl = wm * 128 + i * 16 + ((lane >> 4) << 2) + r;
        const int cl = wn * 64 + j * 16 + (lane & 15);
        float v = acc[i][j][r];
        if (BIAS) v += bias[(long)zi * zsbias + bn + cl];
        if (RELU) v = v > 0.0f ? v : 0.0f;
        const long row = bm + rl;
        const long gi = (long)zi * zsc + row * ldc + bn + cl;
        if (RESID) {
          ((float*)outv)[gi] = b2f(qres[gi]) - b2f(rres[gi]) + v;
        } else {
          ((short*)outv)[gi] = f2b(v);
        }
      }
}

// ------------- merged G2+G3: z = sigmoid(Qh*Kh/16) * Vh -------------
// 256x128 tile, dual accumulators (Kh, Vh) sharing the staged A (rep) tile.
// Same 4-slot pipeline + hoisted addresses.
__global__ __launch_bounds__(512, 2) void gemm_g23(
    const short* __restrict__ rb,    // A: rep bf16 [65536][1024]
    const short* __restrict__ wkt,   // Bk [col][k]
    const short* __restrict__ wvt,   // Bv [col][k]
    const short* __restrict__ gh,    // Qh bf16 [65536][1024]
    short* __restrict__ zb)          // z bf16 out
{
  __shared__ __align__(16) short lA[4 * 8192];     // 64KB: 256 rows x 32k
  __shared__ __align__(16) short lK[4 * 4096];     // 32KB: 128 cols x 32k
  __shared__ __align__(16) short lV[4 * 4096];     // 32KB
  const int lane = threadIdx.x & 63, wave = threadIdx.x >> 6;
  const int wm = wave >> 2, wn = wave & 3;         // per-wave out: 128 x 32
  int bx = blockIdx.x, by = blockIdx.y;
  {
    const int flat = by * 8 + bx;                  // gridDim.x == 8
    const int chunk = (int)(gridDim.x * gridDim.y) >> 3;
    const int fid = (flat & 7) * chunk + (flat >> 3);
    bx = fid & 7; by = fid >> 3;
  }
  const long bm = (long)by * 256;
  const int  bn = bx * 128;

  const short* Ab = rb + bm * 1024;
  const short* Kb = wkt + (long)bn * 1024;
  const short* Vb = wvt + (long)bn * 1024;
  constexpr int NS = 32;                           // K = 1024
  const int g0 = lane >> 4;
  const int arow = wm * 128 + (lane & 15);
  const int bcol = wn * 32 + (lane & 15);

  const char* aP = (const char*)lA + arow * 64 + (((g0 ^ (arow >> 1)) & 3) << 4);
  const char* kP = (const char*)lK + bcol * 64 + (((g0 ^ (bcol >> 1)) & 3) << 4);
  const char* vP = (const char*)lV + bcol * 64 + (((g0 ^ (bcol >> 1)) & 3) << 4);

  const int rw = lane >> 2;
  const int gg = (lane & 3) ^ ((rw >> 1) & 3);
  const short* Asrc = Ab + (wave * 16 + rw) * 1024 + (gg << 3);
  const short* Ksrc = Kb + (wave * 16 + rw) * 1024 + (gg << 3);
  const short* Vsrc = Vb + (wave * 16 + rw) * 1024 + (gg << 3);
  short* lAd = lA + wave * 16 * 32;
  short* lKd = lK + wave * 16 * 32;
  short* lVd = lV + wave * 16 * 32;

  auto stA = [&](int slot, int s) {
    const int sc = s < NS ? s : NS - 1;
    const short* src = Asrc + sc * 32;
    short* d = lAd + slot * 8192;
    __builtin_amdgcn_global_load_lds((const AS1 void*)src,               (AS3 void*)d,        16, 0, 0);
    __builtin_amdgcn_global_load_lds((const AS1 void*)(src + 128*1024),  (AS3 void*)(d+4096), 16, 0, 0);
  };
  auto stKV = [&](int slot, int s) {
    const int sc = s < NS ? s : NS - 1;
    __builtin_amdgcn_global_load_lds((const AS1 void*)(Ksrc + sc * 32), (AS3 void*)(lKd + slot * 4096), 16, 0, 0);
    __builtin_amdgcn_global_load_lds((const AS1 void*)(Vsrc + sc * 32), (AS3 void*)(lVd + slot * 4096), 16, 0, 0);
  };

  // prologue: slices 0,1,2 (12 loads/wave); vmcnt(8) proves slice 0
  stA(0, 0); stKV(0, 0);
  stA(1, 1); stKV(1, 1);
  stA(2, 2); stKV(2, 2);
  asm volatile("s_waitcnt vmcnt(8)" ::: "memory");
  __builtin_amdgcn_s_barrier();

  f32x4 ack[8][2] = {};
  f32x4 acv[8][2] = {};
  bf16x8 bk[2], bv[2];

#define PHASEG(SLOT, MH, LOADB, STAGE_STMT, DOVM)                           \
  {                                                                         \
    if (LOADB) {                                                            \
      _Pragma("unroll")                                                     \
      for (int j = 0; j < 2; ++j) {                                         \
        bk[j] = *(const bf16x8*)(kP + (SLOT) * 8192 + j * 1024);            \
        bv[j] = *(const bf16x8*)(vP + (SLOT) * 8192 + j * 1024);            \
      }                                                                     \
    }                                                                       \
    bf16x8 a[4];                                                            \
    _Pragma("unroll")                                                       \
    for (int i2 = 0; i2 < 4; ++i2)                                          \
      a[i2] = *(const bf16x8*)(aP + (SLOT) * 16384 + (MH) * 4096 + i2 * 1024); \
    STAGE_STMT;                                                             \
    if (DOVM) asm volatile("s_waitcnt vmcnt(8)" ::: "memory");              \
    asm volatile("" ::: "memory");                                          \
    __builtin_amdgcn_s_barrier();                                           \
    __builtin_amdgcn_s_setprio(1);                                          \
    _Pragma("unroll")                                                       \
    for (int i2 = 0; i2 < 4; ++i2)                                          \
      _Pragma("unroll")                                                     \
      for (int j = 0; j < 2; ++j) {                                         \
        ack[(MH) * 4 + i2][j] = __builtin_amdgcn_mfma_f32_16x16x32_bf16(    \
            a[i2], bk[j], ack[(MH) * 4 + i2][j], 0, 0, 0);                  \
        acv[(MH) * 4 + i2][j] = __builtin_amdgcn_mfma_f32_16x16x32_bf16(    \
            a[i2], bv[j], acv[(MH) * 4 + i2][j], 0, 0, 0);                  \
      }                                                                     \
    __builtin_amdgcn_s_setprio(0);                                          \
    asm volatile("" ::: "memory");                                          \
    __builtin_amdgcn_s_barrier();                                           \
  }

  for (int s = 0; s < NS; s += 4) {
    PHASEG(0, 0, true,  stA(3, s + 3), false) PHASEG(0, 1, false, stKV(3, s + 3), true)
    PHASEG(1, 0, true,  stA(0, s + 4), false) PHASEG(1, 1, false, stKV(0, s + 4), true)
    PHASEG(2, 0, true,  stA(1, s + 5), false) PHASEG(2, 1, false, stKV(1, s + 5), true)
    PHASEG(3, 0, true,  stA(2, s + 6), false) PHASEG(3, 1, false, stKV(2, s + 6), true)
  }
#undef PHASEG

  // epilogue: z = sigmoid(Qh * Kh / 16) * Vh
  #pragma unroll
  for (int i = 0; i < 8; ++i)
    #pragma unroll
    for (int j = 0; j < 2; ++j)
      #pragma unroll
      for (int r = 0; r < 4; ++r) {
        const int rl = wm * 128 + i * 16 + ((lane >> 4) << 2) + r;
        const int cl = wn * 32 + j * 16 + (lane & 15);
        const long gi = (bm + rl) * 1024 + bn + cl;
        const float x = b2f(gh[gi]) * ack[i][j][r] * 0.0625f;
        const float gate = 1.0f / (1.0f + __expf(-x));
        zb[gi] = f2b(gate * acv[i][j][r]);
      }
}

extern "C" void kernel_launch(void* const* d_in, const int* in_sizes, int n_in,
                              void* d_out, int out_size, void* d_ws, size_t ws_size,
                              hipStream_t stream) {
  const float* q   = (const float*)d_in[0];
  const float* rep = (const float*)d_in[1];
  const float* Wq  = (const float*)d_in[2];
  const float* Wk  = (const float*)d_in[3];
  const float* Wv  = (const float*)d_in[4];
  const float* W1  = (const float*)d_in[5];
  const float* b1  = (const float*)d_in[6];
  const float* W2  = (const float*)d_in[7];
  const float* b2  = (const float*)d_in[8];
  const float* Ws  = (const float*)d_in[9];
  float* out = (float*)d_out;

  const long NE = 67108864L;   // 65536 * 1024
  char* ws = (char*)d_ws;
  // 4 x 128 MiB slots:
  //   s0: qb (cvt..F)   s1: rb (cvt..F)
  //   s2: gh (G1..G23) -> h1 (M1..M2)
  //   s3: zb (G23..M1) -> ug (M2..F)
  short* qb  = (short*)(ws);
  short* rb  = (short*)(ws + NE * 2);
  short* gh  = (short*)(ws + NE * 4);
  short* zb  = (short*)(ws + NE * 6);
  short* h1b = gh;
  short* ugb = zb;
  char*  wp  = ws + NE * 8;
  short* wqt = (short*)(wp);                 // 2 MiB each
  short* wkt = (short*)(wp + 2097152);
  short* wvt = (short*)(wp + 4194304);
  short* wst = (short*)(wp + 6291456);
  short* w1t = (short*)(wp + 8388608);       // 512 KiB
  short* w2t = (short*)(wp + 8912896);       // 512 KiB

  cvt_bf16<<<4096, 256, 0, stream>>>(q,   qb, NE);
  cvt_bf16<<<4096, 256, 0, stream>>>(rep, rb, NE);
  prep_weights<<<dim3(32, 32, 12), dim3(32, 8), 0, stream>>>(
      Wq, Wk, Wv, W1, W2, Ws, wqt, wkt, wvt, w1t, w2t, wst);

  // G1: Qh = q @ Wq  (bf16 -> gh)
  gemm_bf16<1024, 1024, 1024, false, false, false, true><<<dim3(4, 256), 512, 0, stream>>>(
      qb, 0, wqt, 0, gh, 1024, 0, nullptr, 0, nullptr, nullptr);
  // G23: z = sigmoid(Qh * (rep@Wk) / 16) * (rep@Wv)  -> zb
  gemm_g23<<<dim3(8, 256), 512, 0, stream>>>(rb, wkt, wvt, gh, zb);

  // M1: h1 = relu(z @ W1 + b1), per head (head = blockIdx.z)
  gemm_bf16<256, 1024, 256, true, true, false, false><<<dim3(1, 256, 4), 512, 0, stream>>>(
      zb, 256, w1t, 65536, h1b, 1024, 256, b1, 256, nullptr, nullptr);
  // M2: ug = h1 @ W2 + b2, per head
  gemm_bf16<256, 1024, 256, false, true, false, false><<<dim3(1, 256, 4), 512, 0, stream>>>(
      h1b, 256, w2t, 65536, ugb, 1024, 256, b2, 256, nullptr, nullptr);
  // F: out = (q - rep) + ug @ Ws   (residual from bf16 qb/rb)
  gemm_bf16<1024, 1024, 1024, false, false, true, true><<<dim3(4, 256), 512, 0, stream>>>(
      ugb, 0, wst, 0, out, 1024, 0, nullptr, 0, qb, rb);
}

// Round 13
// 1001.471 us; speedup vs baseline: 1.1500x; 1.0445x over previous
//
#include <hip/hip_runtime.h>
#include <hip/hip_bf16.h>

// TreeHopNode: h = q - rep + (per-head MLP(sigmoid(Qh*Kh/16)*Vh)) @ Ws
// N=65536, E=1024, H=4, G=256, MLP=256. bf16 MFMA 16x16x32, f32 accum.
//
// R13 = R12 (passed, 1046us) with M1+M2 FUSED into gemm_mlp:
//  pass1: h1 = relu(z_h @ W1_h + b1) -> LDS stash (128KB, Latin-square
//         swizzle slot=((k>>3)^row)&31 -> 2-way banks on write and read)
//  pass2: ug_h = h1 @ W2_h + b2 (A from stash, W2 2-slot double-buffer in
//         the remaining 32KB; LDS = 160KB exactly)
// Kills the h1 HBM round-trip (256MB) + one launch + one prologue/epilogue.
// cvt launches merged (grid-z). G1/G23/F unchanged from R12.
// GEMM schedule frozen: R9-R12 proved sync micro-variants are all ~0 delta.

typedef __attribute__((ext_vector_type(8))) short bf16x8;
typedef __attribute__((ext_vector_type(4))) float f32x4;
typedef __attribute__((ext_vector_type(4))) short short4v;

#define AS1 __attribute__((address_space(1)))
#define AS3 __attribute__((address_space(3)))

static __device__ __forceinline__ short f2b(float x) {
  __hip_bfloat16 h = __float2bfloat16(x);
  return __builtin_bit_cast(short, h);
}
static __device__ __forceinline__ float b2f(short s) {
  unsigned u = ((unsigned)(unsigned short)s) << 16;
  return __builtin_bit_cast(float, u);
}

// ---------------- convert f32 -> bf16 (both inputs, one launch) ----------
__global__ void cvt_bf16_2(const float* __restrict__ q, const float* __restrict__ rep,
                           short* __restrict__ qb, short* __restrict__ rb, long n) {
  const float* __restrict__ in = blockIdx.z ? rep : q;
  short* __restrict__ out = blockIdx.z ? rb : qb;
  long i = ((long)blockIdx.x * blockDim.x + threadIdx.x) * 4;
  const long stride = (long)gridDim.x * blockDim.x * 4;
  for (; i < n; i += stride) {
    float4 v = *(const float4*)(in + i);
    short4v o = { f2b(v.x), f2b(v.y), f2b(v.z), f2b(v.w) };
    *(short4v*)(out + i) = o;
  }
}

// ---------------- transpose + convert weights ----------------
__global__ void prep_weights(
    const float* __restrict__ Wq, const float* __restrict__ Wk, const float* __restrict__ Wv,
    const float* __restrict__ W1, const float* __restrict__ W2, const float* __restrict__ Ws,
    short* __restrict__ wqt, short* __restrict__ wkt, short* __restrict__ wvt,
    short* __restrict__ w1t, short* __restrict__ w2t, short* __restrict__ wst)
{
  const int job = blockIdx.z;
  const float* src; short* dst; int R, C;
  if (job < 3)       { src = (job==0)?Wq:((job==1)?Wk:Wv); dst = (job==0)?wqt:((job==1)?wkt:wvt); R = 1024; C = 1024; }
  else if (job == 3) { src = Ws; dst = wst; R = 1024; C = 1024; }
  else if (job < 8)  { int h = job-4; src = W1 + h*65536; dst = w1t + h*65536; R = 256; C = 256; }
  else               { int h = job-8; src = W2 + h*65536; dst = w2t + h*65536; R = 256; C = 256; }
  const int c0 = blockIdx.x * 32, r0 = blockIdx.y * 32;
  if (c0 >= C || r0 >= R) return;
  __shared__ float t[32][33];
  for (int i = threadIdx.y; i < 32; i += 8)
    t[i][threadIdx.x] = src[(long)(r0 + i) * C + c0 + threadIdx.x];
  __syncthreads();
  for (int i = threadIdx.y; i < 32; i += 8)
    dst[(long)(c0 + i) * R + r0 + threadIdx.x] = f2b(t[threadIdx.x][i]);
}

// ---------------- 256x256-tile bf16 GEMM, 4-slot pipeline (R12) ---------
template <int KDIM, int LDA, int LDB, bool RELU, bool BIAS, bool RESID, bool SWZ>
__global__ __launch_bounds__(512, 2) void gemm_bf16(
    const short* __restrict__ A, long zsa,
    const short* __restrict__ Bt, long zsb,
    void* __restrict__ outv, long ldc, long zsc,
    const float* __restrict__ bias, long zsbias,
    const short* __restrict__ qres, const short* __restrict__ rres)
{
  __shared__ __align__(16) short lA[4 * 8192];     // 4 slots of [256][32]
  __shared__ __align__(16) short lB[4 * 8192];
  const int lane = threadIdx.x & 63, wave = threadIdx.x >> 6;
  const int wm = wave >> 2, wn = wave & 3;         // 2M x 4N wave grid
  int bx = blockIdx.x, by = blockIdx.y;
  if (SWZ) {
    const int nbx = gridDim.x;
    const int flat = by * nbx + bx;
    const int chunk = (int)(gridDim.x * gridDim.y) >> 3;
    const int fid = (flat & 7) * chunk + (flat >> 3);
    bx = fid % nbx; by = fid / nbx;
  }
  const long bm = (long)by * 256;
  const int  bn = bx * 256;
  const int  zi = blockIdx.z;

  const short* Ab = A + (long)zi * zsa + bm * LDA;
  const short* Bb = Bt + (long)zi * zsb + (long)bn * LDB;
  constexpr int NS = KDIM / 32;                    // k-slices (32 wide)
  const int g0 = lane >> 4;
  const int arow = wm * 128 + (lane & 15);
  const int bcol = wn * 64 + (lane & 15);

  const char* aP = (const char*)lA + arow * 64 + (((g0 ^ (arow >> 1)) & 3) << 4);
  const char* bP = (const char*)lB + bcol * 64 + (((g0 ^ (bcol >> 1)) & 3) << 4);

  const int rw = lane >> 2;
  const int gg = (lane & 3) ^ ((rw >> 1) & 3);
  const short* Asrc = Ab + (wave * 16 + rw) * LDA + (gg << 3);
  const short* Bsrc = Bb + (wave * 16 + rw) * LDB + (gg << 3);
  short* lAd = lA + wave * 16 * 32;
  short* lBd = lB + wave * 16 * 32;

  auto stA = [&](int slot, int s) {
    const int sc = s < NS ? s : NS - 1;            // tail: clamp SOURCE only
    const short* src = Asrc + sc * 32;
    short* d = lAd + slot * 8192;
    __builtin_amdgcn_global_load_lds((const AS1 void*)src,              (AS3 void*)d,        16, 0, 0);
    __builtin_amdgcn_global_load_lds((const AS1 void*)(src + 128*LDA),  (AS3 void*)(d+4096), 16, 0, 0);
  };
  auto stB = [&](int slot, int s) {
    const int sc = s < NS ? s : NS - 1;
    const short* src = Bsrc + sc * 32;
    short* d = lBd + slot * 8192;
    __builtin_amdgcn_global_load_lds((const AS1 void*)src,              (AS3 void*)d,        16, 0, 0);
    __builtin_amdgcn_global_load_lds((const AS1 void*)(src + 128*LDB),  (AS3 void*)(d+4096), 16, 0, 0);
  };

  stA(0, 0); stB(0, 0);
  stA(1, 1); stB(1, 1);
  stA(2, 2); stB(2, 2);
  asm volatile("s_waitcnt vmcnt(8)" ::: "memory");
  __builtin_amdgcn_s_barrier();

  f32x4 acc[8][4] = {};
  bf16x8 b[4];

#define PHASE(SLOT, MH, LOADB, STAGE_STMT, DOVM)                            \
  {                                                                         \
    if (LOADB) {                                                            \
      _Pragma("unroll")                                                     \
      for (int j = 0; j < 4; ++j)                                           \
        b[j] = *(const bf16x8*)(bP + (SLOT) * 16384 + j * 1024);            \
    }                                                                       \
    bf16x8 a[4];                                                            \
    _Pragma("unroll")                                                       \
    for (int i2 = 0; i2 < 4; ++i2)                                          \
      a[i2] = *(const bf16x8*)(aP + (SLOT) * 16384 + (MH) * 4096 + i2 * 1024); \
    STAGE_STMT;                                                             \
    if (DOVM) asm volatile("s_waitcnt vmcnt(8)" ::: "memory");              \
    asm volatile("" ::: "memory");                                          \
    __builtin_amdgcn_s_barrier();                                           \
    __builtin_amdgcn_s_setprio(1);                                          \
    _Pragma("unroll")                                                       \
    for (int i2 = 0; i2 < 4; ++i2)                                          \
      _Pragma("unroll")                                                     \
      for (int j = 0; j < 4; ++j)                                           \
        acc[(MH) * 4 + i2][j] = __builtin_amdgcn_mfma_f32_16x16x32_bf16(    \
            a[i2], b[j], acc[(MH) * 4 + i2][j], 0, 0, 0);                   \
    __builtin_amdgcn_s_setprio(0);                                          \
    asm volatile("" ::: "memory");                                          \
    __builtin_amdgcn_s_barrier();                                           \
  }

  for (int s = 0; s < NS; s += 4) {
    PHASE(0, 0, true,  stA(3, s + 3), false) PHASE(0, 1, false, stB(3, s + 3), true)
    PHASE(1, 0, true,  stA(0, s + 4), false) PHASE(1, 1, false, stB(0, s + 4), true)
    PHASE(2, 0, true,  stA(1, s + 5), false) PHASE(2, 1, false, stB(1, s + 5), true)
    PHASE(3, 0, true,  stA(2, s + 6), false) PHASE(3, 1, false, stB(2, s + 6), true)
  }
#undef PHASE

  // epilogue; C/D layout: col=lane&15, row=(lane>>4)*4+reg (m89)
  #pragma unroll
  for (int i = 0; i < 8; ++i)
    #pragma unroll
    for (int j = 0; j < 4; ++j)
      #pragma unroll
      for (int r = 0; r < 4; ++r) {
        const int rl = wm * 128 + i * 16 + ((lane >> 4) << 2) + r;
        const int cl = wn * 64 + j * 16 + (lane & 15);
        float v = acc[i][j][r];
        if (BIAS) v += bias[(long)zi * zsbias + bn + cl];
        if (RELU) v = v > 0.0f ? v : 0.0f;
        const long row = bm + rl;
        const long gi = (long)zi * zsc + row * ldc + bn + cl;
        if (RESID) {
          ((float*)outv)[gi] = b2f(qres[gi]) - b2f(rres[gi]) + v;
        } else {
          ((short*)outv)[gi] = f2b(v);
        }
      }
}

// ------------- merged G2+G3: z = sigmoid(Qh*Kh/16) * Vh (R12) -----------
__global__ __launch_bounds__(512, 2) void gemm_g23(
    const short* __restrict__ rb, const short* __restrict__ wkt,
    const short* __restrict__ wvt, const short* __restrict__ gh,
    short* __restrict__ zb)
{
  __shared__ __align__(16) short lA[4 * 8192];
  __shared__ __align__(16) short lK[4 * 4096];
  __shared__ __align__(16) short lV[4 * 4096];
  const int lane = threadIdx.x & 63, wave = threadIdx.x >> 6;
  const int wm = wave >> 2, wn = wave & 3;
  int bx = blockIdx.x, by = blockIdx.y;
  {
    const int flat = by * 8 + bx;
    const int chunk = (int)(gridDim.x * gridDim.y) >> 3;
    const int fid = (flat & 7) * chunk + (flat >> 3);
    bx = fid & 7; by = fid >> 3;
  }
  const long bm = (long)by * 256;
  const int  bn = bx * 128;

  const short* Ab = rb + bm * 1024;
  const short* Kb = wkt + (long)bn * 1024;
  const short* Vb = wvt + (long)bn * 1024;
  constexpr int NS = 32;
  const int g0 = lane >> 4;
  const int arow = wm * 128 + (lane & 15);
  const int bcol = wn * 32 + (lane & 15);

  const char* aP = (const char*)lA + arow * 64 + (((g0 ^ (arow >> 1)) & 3) << 4);
  const char* kP = (const char*)lK + bcol * 64 + (((g0 ^ (bcol >> 1)) & 3) << 4);
  const char* vP = (const char*)lV + bcol * 64 + (((g0 ^ (bcol >> 1)) & 3) << 4);

  const int rw = lane >> 2;
  const int gg = (lane & 3) ^ ((rw >> 1) & 3);
  const short* Asrc = Ab + (wave * 16 + rw) * 1024 + (gg << 3);
  const short* Ksrc = Kb + (wave * 16 + rw) * 1024 + (gg << 3);
  const short* Vsrc = Vb + (wave * 16 + rw) * 1024 + (gg << 3);
  short* lAd = lA + wave * 16 * 32;
  short* lKd = lK + wave * 16 * 32;
  short* lVd = lV + wave * 16 * 32;

  auto stA = [&](int slot, int s) {
    const int sc = s < NS ? s : NS - 1;
    const short* src = Asrc + sc * 32;
    short* d = lAd + slot * 8192;
    __builtin_amdgcn_global_load_lds((const AS1 void*)src,               (AS3 void*)d,        16, 0, 0);
    __builtin_amdgcn_global_load_lds((const AS1 void*)(src + 128*1024),  (AS3 void*)(d+4096), 16, 0, 0);
  };
  auto stKV = [&](int slot, int s) {
    const int sc = s < NS ? s : NS - 1;
    __builtin_amdgcn_global_load_lds((const AS1 void*)(Ksrc + sc * 32), (AS3 void*)(lKd + slot * 4096), 16, 0, 0);
    __builtin_amdgcn_global_load_lds((const AS1 void*)(Vsrc + sc * 32), (AS3 void*)(lVd + slot * 4096), 16, 0, 0);
  };

  stA(0, 0); stKV(0, 0);
  stA(1, 1); stKV(1, 1);
  stA(2, 2); stKV(2, 2);
  asm volatile("s_waitcnt vmcnt(8)" ::: "memory");
  __builtin_amdgcn_s_barrier();

  f32x4 ack[8][2] = {};
  f32x4 acv[8][2] = {};
  bf16x8 bk[2], bv[2];

#define PHASEG(SLOT, MH, LOADB, STAGE_STMT, DOVM)                           \
  {                                                                         \
    if (LOADB) {                                                            \
      _Pragma("unroll")                                                     \
      for (int j = 0; j < 2; ++j) {                                         \
        bk[j] = *(const bf16x8*)(kP + (SLOT) * 8192 + j * 1024);            \
        bv[j] = *(const bf16x8*)(vP + (SLOT) * 8192 + j * 1024);            \
      }                                                                     \
    }                                                                       \
    bf16x8 a[4];                                                            \
    _Pragma("unroll")                                                       \
    for (int i2 = 0; i2 < 4; ++i2)                                          \
      a[i2] = *(const bf16x8*)(aP + (SLOT) * 16384 + (MH) * 4096 + i2 * 1024); \
    STAGE_STMT;                                                             \
    if (DOVM) asm volatile("s_waitcnt vmcnt(8)" ::: "memory");              \
    asm volatile("" ::: "memory");                                          \
    __builtin_amdgcn_s_barrier();                                           \
    __builtin_amdgcn_s_setprio(1);                                          \
    _Pragma("unroll")                                                       \
    for (int i2 = 0; i2 < 4; ++i2)                                          \
      _Pragma("unroll")                                                     \
      for (int j = 0; j < 2; ++j) {                                         \
        ack[(MH) * 4 + i2][j] = __builtin_amdgcn_mfma_f32_16x16x32_bf16(    \
            a[i2], bk[j], ack[(MH) * 4 + i2][j], 0, 0, 0);                  \
        acv[(MH) * 4 + i2][j] = __builtin_amdgcn_mfma_f32_16x16x32_bf16(    \
            a[i2], bv[j], acv[(MH) * 4 + i2][j], 0, 0, 0);                  \
      }                                                                     \
    __builtin_amdgcn_s_setprio(0);                                          \
    asm volatile("" ::: "memory");                                          \
    __builtin_amdgcn_s_barrier();                                           \
  }

  for (int s = 0; s < NS; s += 4) {
    PHASEG(0, 0, true,  stA(3, s + 3), false) PHASEG(0, 1, false, stKV(3, s + 3), true)
    PHASEG(1, 0, true,  stA(0, s + 4), false) PHASEG(1, 1, false, stKV(0, s + 4), true)
    PHASEG(2, 0, true,  stA(1, s + 5), false) PHASEG(2, 1, false, stKV(1, s + 5), true)
    PHASEG(3, 0, true,  stA(2, s + 6), false) PHASEG(3, 1, false, stKV(2, s + 6), true)
  }
#undef PHASEG

  #pragma unroll
  for (int i = 0; i < 8; ++i)
    #pragma unroll
    for (int j = 0; j < 2; ++j)
      #pragma unroll
      for (int r = 0; r < 4; ++r) {
        const int rl = wm * 128 + i * 16 + ((lane >> 4) << 2) + r;
        const int cl = wn * 32 + j * 16 + (lane & 15);
        const long gi = (bm + rl) * 1024 + bn + cl;
        const float x = b2f(gh[gi]) * ack[i][j][r] * 0.0625f;
        const float gate = 1.0f / (1.0f + __expf(-x));
        zb[gi] = f2b(gate * acv[i][j][r]);
      }
}

// ------------- fused MLP: ug = relu(z_h @ W1_h + b1) @ W2_h + b2 --------
// One block = 256 rows x one head. Pass1 -> h1 in LDS stash (Latin-square
// swizzle slot=((k>>3)^row)&31, 512B rows -> 2-way banks). Pass2 reads the
// stash as A, W2 double-buffered in the 32KB tail. LDS = 160KB exactly.
__global__ __launch_bounds__(512) void gemm_mlp(
    const short* __restrict__ zb, const short* __restrict__ w1t,
    const short* __restrict__ w2t, const float* __restrict__ b1,
    const float* __restrict__ b2, short* __restrict__ ug)
{
  __shared__ __align__(16) char smem[163840];
  short* lA = (short*)smem;                        // pass1: 4 x 16KB
  short* lB = (short*)(smem + 65536);              // pass1: 4 x 16KB
  short* stash = (short*)smem;                     // h1: 128KB (after pass1)
  short* w2b = (short*)(smem + 131072);            // pass2 B: 2 x 16KB

  const int lane = threadIdx.x & 63, wave = threadIdx.x >> 6;
  const int wm = wave >> 2, wn = wave & 3;
  const long bm = (long)blockIdx.y * 256;
  const int head = blockIdx.z;

  const int g0 = lane >> 4;
  const int arow = wm * 128 + (lane & 15);
  const int bcol = wn * 64 + (lane & 15);
  const int rw = lane >> 2;
  const int gg = (lane & 3) ^ ((rw >> 1) & 3);

  // ---------- pass 1: h1 = relu(z_h @ W1_h + b1) ----------
  {
    const short* Ab = zb + bm * 1024 + head * 256;
    const short* Bb = w1t + head * 65536;
    const char* aP = (const char*)lA + arow * 64 + (((g0 ^ (arow >> 1)) & 3) << 4);
    const char* bP = (const char*)lB + bcol * 64 + (((g0 ^ (bcol >> 1)) & 3) << 4);
    const short* Asrc = Ab + (wave * 16 + rw) * 1024 + (gg << 3);
    const short* Bsrc = Bb + (wave * 16 + rw) * 256 + (gg << 3);
    short* lAd = lA + wave * 16 * 32;
    short* lBd = lB + wave * 16 * 32;

    auto stA = [&](int slot, int s) {
      const int sc = s < 8 ? s : 7;
      const short* src = Asrc + sc * 32;
      short* d = lAd + slot * 8192;
      __builtin_amdgcn_global_load_lds((const AS1 void*)src,              (AS3 void*)d,        16, 0, 0);
      __builtin_amdgcn_global_load_lds((const AS1 void*)(src + 128*1024), (AS3 void*)(d+4096), 16, 0, 0);
    };
    auto stB = [&](int slot, int s) {
      const int sc = s < 8 ? s : 7;
      const short* src = Bsrc + sc * 32;
      short* d = lBd + slot * 8192;
      __builtin_amdgcn_global_load_lds((const AS1 void*)src,              (AS3 void*)d,        16, 0, 0);
      __builtin_amdgcn_global_load_lds((const AS1 void*)(src + 128*256),  (AS3 void*)(d+4096), 16, 0, 0);
    };

    stA(0, 0); stB(0, 0);
    stA(1, 1); stB(1, 1);
    stA(2, 2); stB(2, 2);
    asm volatile("s_waitcnt vmcnt(8)" ::: "memory");
    __builtin_amdgcn_s_barrier();

    f32x4 acc[8][4] = {};
    bf16x8 b[4];

#define PHASE1(SLOT, MH, LOADB, STAGE_STMT, DOVM)                           \
    {                                                                       \
      if (LOADB) {                                                          \
        _Pragma("unroll")                                                   \
        for (int j = 0; j < 4; ++j)                                         \
          b[j] = *(const bf16x8*)(bP + (SLOT) * 16384 + j * 1024);          \
      }                                                                     \
      bf16x8 a[4];                                                          \
      _Pragma("unroll")                                                     \
      for (int i2 = 0; i2 < 4; ++i2)                                        \
        a[i2] = *(const bf16x8*)(aP + (SLOT) * 16384 + (MH) * 4096 + i2 * 1024); \
      STAGE_STMT;                                                           \
      if (DOVM) asm volatile("s_waitcnt vmcnt(8)" ::: "memory");            \
      asm volatile("" ::: "memory");                                        \
      __builtin_amdgcn_s_barrier();                                         \
      __builtin_amdgcn_s_setprio(1);                                        \
      _Pragma("unroll")                                                     \
      for (int i2 = 0; i2 < 4; ++i2)                                        \
        _Pragma("unroll")                                                   \
        for (int j = 0; j < 4; ++j)                                         \
          acc[(MH) * 4 + i2][j] = __builtin_amdgcn_mfma_f32_16x16x32_bf16(  \
              a[i2], b[j], acc[(MH) * 4 + i2][j], 0, 0, 0);                 \
      __builtin_amdgcn_s_setprio(0);                                        \
      asm volatile("" ::: "memory");                                        \
      __builtin_amdgcn_s_barrier();                                         \
    }

    for (int s = 0; s < 8; s += 4) {
      PHASE1(0, 0, true,  stA(3, s + 3), false) PHASE1(0, 1, false, stB(3, s + 3), true)
      PHASE1(1, 0, true,  stA(0, s + 4), false) PHASE1(1, 1, false, stB(0, s + 4), true)
      PHASE1(2, 0, true,  stA(1, s + 5), false) PHASE1(2, 1, false, stB(1, s + 5), true)
      PHASE1(3, 0, true,  stA(2, s + 6), false) PHASE1(3, 1, false, stB(2, s + 6), true)
    }
#undef PHASE1

    __syncthreads();     // all pass-1 LDS reads done before stash overwrite
    #pragma unroll
    for (int i = 0; i < 8; ++i)
      #pragma unroll
      for (int j = 0; j < 4; ++j)
        #pragma unroll
        for (int r = 0; r < 4; ++r) {
          const int rl = wm * 128 + i * 16 + ((lane >> 4) << 2) + r;
          const int cl = wn * 64 + j * 16 + (lane & 15);
          float v = acc[i][j][r] + b1[head * 256 + cl];
          v = v > 0.0f ? v : 0.0f;
          stash[rl * 256 + ((((cl >> 3) ^ rl) & 31) << 3) + (cl & 7)] = f2b(v);
        }
    __syncthreads();     // stash complete before pass-2 reads
  }

  // ---------- pass 2: ug = h1 @ W2_h + b2 ----------
  {
    const short* Wb = w2t + head * 65536;
    const short* Bsrc2 = Wb + (wave * 16 + rw) * 256 + (gg << 3);
    short* lBd2 = w2b + wave * 16 * 32;
    const char* b2P = (const char*)w2b + bcol * 64 + (((g0 ^ (bcol >> 1)) & 3) << 4);

    auto stW = [&](int slot, int s) {
      const int sc = s < 8 ? s : 7;
      const short* src = Bsrc2 + sc * 32;
      short* d = lBd2 + slot * 8192;
      __builtin_amdgcn_global_load_lds((const AS1 void*)src,             (AS3 void*)d,        16, 0, 0);
      __builtin_amdgcn_global_load_lds((const AS1 void*)(src + 128*256), (AS3 void*)(d+4096), 16, 0, 0);
    };

    stW(0, 0);
    asm volatile("s_waitcnt vmcnt(0)" ::: "memory");
    __builtin_amdgcn_s_barrier();

    f32x4 acc2[8][4] = {};
    bf16x8 br[4];

    for (int s = 0; s < 8; ++s) {
      const int sl = s & 1;
      const int ks = s * 4 + g0;       // 16B k-slot index in stash

#define PHASE2(MH, LOADB, STAGE_STMT, DOVM)                                 \
      {                                                                     \
        if (LOADB) {                                                        \
          _Pragma("unroll")                                                 \
          for (int j = 0; j < 4; ++j)                                       \
            br[j] = *(const bf16x8*)(b2P + sl * 16384 + j * 1024);          \
        }                                                                   \
        bf16x8 a[4];                                                        \
        _Pragma("unroll")                                                   \
        for (int i2 = 0; i2 < 4; ++i2) {                                    \
          const int row = arow + (MH) * 64 + i2 * 16;                       \
          a[i2] = *(const bf16x8*)(stash + row * 256 + (((ks ^ row) & 31) << 3)); \
        }                                                                   \
        STAGE_STMT;                                                         \
        if (DOVM) asm volatile("s_waitcnt vmcnt(0)" ::: "memory");          \
        asm volatile("" ::: "memory");                                      \
        __builtin_amdgcn_s_barrier();                                       \
        __builtin_amdgcn_s_setprio(1);                                      \
        _Pragma("unroll")                                                   \
        for (int i2 = 0; i2 < 4; ++i2)                                      \
          _Pragma("unroll")                                                 \
          for (int j = 0; j < 4; ++j)                                       \
            acc2[(MH) * 4 + i2][j] = __builtin_amdgcn_mfma_f32_16x16x32_bf16( \
                a[i2], br[j], acc2[(MH) * 4 + i2][j], 0, 0, 0);             \
        __builtin_amdgcn_s_setprio(0);                                      \
        asm volatile("" ::: "memory");                                      \
        __builtin_amdgcn_s_barrier();                                       \
      }

      PHASE2(0, true,  stW(sl ^ 1, s + 1), false)
      PHASE2(1, false, {}, true)
#undef PHASE2
    }

    #pragma unroll
    for (int i = 0; i < 8; ++i)
      #pragma unroll
      for (int j = 0; j < 4; ++j)
        #pragma unroll
        for (int r = 0; r < 4; ++r) {
          const int rl = wm * 128 + i * 16 + ((lane >> 4) << 2) + r;
          const int cl = wn * 64 + j * 16 + (lane & 15);
          const float v = acc2[i][j][r] + b2[head * 256 + cl];
          ug[(bm + rl) * 1024 + head * 256 + cl] = f2b(v);
        }
  }
}

extern "C" void kernel_launch(void* const* d_in, const int* in_sizes, int n_in,
                              void* d_out, int out_size, void* d_ws, size_t ws_size,
                              hipStream_t stream) {
  const float* q   = (const float*)d_in[0];
  const float* rep = (const float*)d_in[1];
  const float* Wq  = (const float*)d_in[2];
  const float* Wk  = (const float*)d_in[3];
  const float* Wv  = (const float*)d_in[4];
  const float* W1  = (const float*)d_in[5];
  const float* b1  = (const float*)d_in[6];
  const float* W2  = (const float*)d_in[7];
  const float* b2  = (const float*)d_in[8];
  const float* Ws  = (const float*)d_in[9];
  float* out = (float*)d_out;

  const long NE = 67108864L;   // 65536 * 1024
  char* ws = (char*)d_ws;
  // 4 x 128 MiB slots:
  //   s0: qb (cvt..F)   s1: rb (cvt..F)
  //   s2: gh (G1..G23) -> ug (mlp..F)
  //   s3: zb (G23..mlp)
  short* qb  = (short*)(ws);
  short* rb  = (short*)(ws + NE * 2);
  short* gh  = (short*)(ws + NE * 4);
  short* zb  = (short*)(ws + NE * 6);
  short* ugb = gh;
  char*  wp  = ws + NE * 8;
  short* wqt = (short*)(wp);                 // 2 MiB each
  short* wkt = (short*)(wp + 2097152);
  short* wvt = (short*)(wp + 4194304);
  short* wst = (short*)(wp + 6291456);
  short* w1t = (short*)(wp + 8388608);       // 512 KiB
  short* w2t = (short*)(wp + 8912896);       // 512 KiB

  cvt_bf16_2<<<dim3(2048, 1, 2), 256, 0, stream>>>(q, rep, qb, rb, NE);
  prep_weights<<<dim3(32, 32, 12), dim3(32, 8), 0, stream>>>(
      Wq, Wk, Wv, W1, W2, Ws, wqt, wkt, wvt, w1t, w2t, wst);

  // G1: Qh = q @ Wq  (bf16 -> gh)
  gemm_bf16<1024, 1024, 1024, false, false, false, true><<<dim3(4, 256), 512, 0, stream>>>(
      qb, 0, wqt, 0, gh, 1024, 0, nullptr, 0, nullptr, nullptr);
  // G23: z = sigmoid(Qh * (rep@Wk) / 16) * (rep@Wv)  -> zb
  gemm_g23<<<dim3(8, 256), 512, 0, stream>>>(rb, wkt, wvt, gh, zb);
  // fused MLP: ug = relu(z@W1+b1)@W2+b2  (h1 never leaves LDS)
  gemm_mlp<<<dim3(1, 256, 4), 512, 0, stream>>>(zb, w1t, w2t, b1, b2, ugb);
  // F: out = (q - rep) + ug @ Ws   (residual from bf16 qb/rb)
  gemm_bf16<1024, 1024, 1024, false, false, true, true><<<dim3(4, 256), 512, 0, stream>>>(
      ugb, 0, wst, 0, out, 1024, 0, nullptr, 0, qb, rb);
}